// Round 7
// baseline (77.751 us; speedup 1.0000x reference)
//
#include <hip/hip_runtime.h>
#include <hip/hip_bf16.h>

using bf16x8 = __attribute__((ext_vector_type(8))) short;
using f32x4  = __attribute__((ext_vector_type(4))) float;

__device__ __forceinline__ unsigned short f2bf(float x) {
    unsigned int u = __float_as_uint(x);
    return (unsigned short)((u + 0x7FFFu + ((u >> 16) & 1u)) >> 16);
}

__device__ __forceinline__ void gload_lds16(const float* g, float* l) {
    __builtin_amdgcn_global_load_lds(
        (__attribute__((address_space(1))) void*)(g),
        (__attribute__((address_space(3))) void*)(l), 16, 0, 0);
}

// -------------------------------------------------------------------------
// K0: pack text_embeddings [91][512] f32 -> [96][512] bf16 (rows 91..95 = 0)
// -------------------------------------------------------------------------
__global__ __launch_bounds__(256)
void k_prep(const float* __restrict__ te, unsigned short* __restrict__ te_bf) {
    const int r = blockIdx.x;            // 0..95
    for (int i = threadIdx.x; i < 512; i += 256) {
        const float v = (r < 91) ? te[(size_t)r * 512 + i] : 0.f;
        te_bf[(size_t)r * 512 + i] = f2bf(v);
    }
}

// -------------------------------------------------------------------------
// K1v2: ccombo[n][c] = focal(logits[n][c]) + 0.5*(1 - <v_norm[n], te[c]>)
// grid 1024, block 256 = 16 rows. Embed tile staged via global_load_lds
// (async, 8 KB in flight per wave) into 2064-B padded rows (conflict-free
// ds_read_b128). No K-split: wave w owns ct {w, w+4 (w<2)} over full K=512.
// -------------------------------------------------------------------------
__global__ __launch_bounds__(256)
void k_class_embed(const float* __restrict__ logits,       // [16384][91]
                   const float* __restrict__ embed,        // [16384][512]
                   const unsigned short* __restrict__ te_bf, // [96][512] bf16
                   float* __restrict__ ccombo)             // [16384][96]
{
    __shared__ float a_tile[16 * 516];     // 33024 B, rows padded +4 floats

    const int tid  = threadIdx.x;
    const int lane = tid & 63;
    const int wv   = tid >> 6;
    const int r16  = lane & 15;
    const int q    = lane >> 4;
    const int n0   = blockIdx.x * 16;

    // async stage: 32 chunks of 1 KB (row r, half h), 8 per wave
#pragma unroll
    for (int i = 0; i < 8; ++i) {
        const int c = wv * 8 + i;          // 0..31, wave-uniform
        const int r = c >> 1, h = c & 1;
        const float* g = embed + (size_t)(n0 + r) * 512 + h * 256 + lane * 4;
        float* l = &a_tile[r * 516 + h * 256];
        gload_lds16(g, l);
    }
    __syncthreads();

    f32x4 acc0 = (f32x4){0.f, 0.f, 0.f, 0.f};
    f32x4 acc1 = (f32x4){0.f, 0.f, 0.f, 0.f};
    float sumsq = 0.f;

    const float* ar = &a_tile[r16 * 516 + q * 8];
    const unsigned short* brow0 = te_bf + (size_t)(wv * 16 + r16) * 512 + q * 8;
    const unsigned short* brow1 = te_bf + (size_t)((wv + 4) * 16 + r16) * 512 + q * 8;

#pragma unroll
    for (int ks = 0; ks < 16; ++ks) {
        const float4 a0 = *(const float4*)(ar + ks * 32);
        const float4 a1 = *(const float4*)(ar + ks * 32 + 4);
        const float fv[8] = {a0.x, a0.y, a0.z, a0.w, a1.x, a1.y, a1.z, a1.w};
        bf16x8 af;
#pragma unroll
        for (int j = 0; j < 8; ++j) {
            sumsq += fv[j] * fv[j];
            af[j] = (short)f2bf(fv[j]);
        }
        const bf16x8 bf0 = *(const bf16x8*)(brow0 + ks * 32);
        acc0 = __builtin_amdgcn_mfma_f32_16x16x32_bf16(af, bf0, acc0, 0, 0, 0);
        if (wv < 2) {
            const bf16x8 bf1 = *(const bf16x8*)(brow1 + ks * 32);
            acc1 = __builtin_amdgcn_mfma_f32_16x16x32_bf16(af, bf1, acc1, 0, 0, 0);
        }
    }

    // full-row sumsq: lanes {l, l^16, l^32, l^48} hold q-slices of row r16
    sumsq += __shfl_xor(sumsq, 16);
    sumsq += __shfl_xor(sumsq, 32);
    const float rnorm_own = rsqrtf(sumsq);
    float rn[4];
#pragma unroll
    for (int j = 0; j < 4; ++j) rn[j] = __shfl(rnorm_own, q * 4 + j);

#pragma unroll
    for (int t = 0; t < 2; ++t) {
        if (t == 1 && wv >= 2) break;
        const int ct = (t == 0) ? wv : wv + 4;
        const f32x4 acc = (t == 0) ? acc0 : acc1;
        const int c = ct * 16 + r16;
        if (c < 91) {
#pragma unroll
            for (int j = 0; j < 4; ++j) {
                const int n = n0 + q * 4 + j;           // C/D: row=(lane>>4)*4+reg
                const float dot = acc[j] * rn[j];
                const float x = logits[(size_t)n * 91 + c];
                const float p = 1.f / (1.f + __expf(-x));
                const float pos = 0.25f * (1.f - p) * (1.f - p) * (-__logf(p + 1e-8f));
                const float neg = 0.75f * p * p * (-__logf(1.f - p + 1e-8f));
                ccombo[(size_t)n * 96 + c] = (pos - neg) + 0.5f - 0.5f * dot;
            }
        }
    }
}

// -------------------------------------------------------------------------
// K2v4: out[n][m] = ccombo[n][id[m]] + L1 - GIoU
// grid 512 n-chunks x 25 m-chunks (exact: 32 n x 64 m per block, 0 waste).
// Thread = one m-box for 8 n-rows (nl = wv*8 + p, contiguous per wave).
// cc gather: ccT[96][36] transposed -> 2x ds_read_b128 per thread total.
// -------------------------------------------------------------------------
__global__ __launch_bounds__(256, 8)
void k_cost(const float* __restrict__ pboxes,   // [16384][4] cxcywh
            const float* __restrict__ tboxes,   // [1600][4]  cxcywh
            const int*   __restrict__ tids,     // [1600]
            const float* __restrict__ ccombo,   // [16384][96]
            float* __restrict__ out)            // [16384][1600]
{
    __shared__ float ccT[96 * 36];    // 13824 B, transposed + pad 36

    const int tid    = threadIdx.x;
    const int bx     = blockIdx.x;
    const int mchunk = bx % 25;               // 25 chunks of 64 m
    const int nchunk = bx / 25;               // 512 chunks of 32 n
    const int n0     = nchunk * 32;

    // stage cc transposed: ccT[col][row] for rows n0..n0+31
    for (int e = tid; e < 32 * 96; e += 256) {
        const int row = e / 96, col = e - row * 96;
        ccT[col * 36 + row] = ccombo[(size_t)n0 * 96 + e];
    }

    // per-thread m-box in registers
    const int lane = tid & 63;
    const int wv   = tid >> 6;
    const int m    = mchunk * 64 + lane;      // < 1600 always
    const float4 b = *(const float4*)(tboxes + (size_t)m * 4);
    const float tcx = b.x, tcy = b.y, tw = b.z, th = b.w;
    const float tx0 = __builtin_fmaf(-0.5f, tw, tcx);
    const float ty0 = __builtin_fmaf(-0.5f, th, tcy);
    const float tx1 = __builtin_fmaf( 0.5f, tw, tcx);
    const float ty1 = __builtin_fmaf( 0.5f, th, tcy);
    const float ta  = tw * th;
    const int   id  = tids[m];
    __syncthreads();

    // preload this thread's 8 cc values (column id, rows wv*8..wv*8+7)
    const float4 ccA = *(const float4*)&ccT[id * 36 + wv * 8];
    const float4 ccB = *(const float4*)&ccT[id * 36 + wv * 8 + 4];
    const float ccv[8] = {ccA.x, ccA.y, ccA.z, ccA.w, ccB.x, ccB.y, ccB.z, ccB.w};

    float* obase = out + (size_t)(n0 + wv * 8) * 1600 + m;

#pragma unroll
    for (int p = 0; p < 8; ++p) {
        const int nlu = __builtin_amdgcn_readfirstlane(n0 + wv * 8 + p);
        const float4 PB = *(const float4*)(pboxes + (size_t)nlu * 4);   // s_load
        const float pcx = PB.x, pcy = PB.y, pw = PB.z, ph = PB.w;
        const float px0 = __builtin_fmaf(-0.5f, pw, pcx);
        const float py0 = __builtin_fmaf(-0.5f, ph, pcy);
        const float px1 = __builtin_fmaf( 0.5f, pw, pcx);
        const float py1 = __builtin_fmaf( 0.5f, ph, pcy);
        const float pa  = pw * ph;

        const float dx = fminf(px1, tx1) - fmaxf(px0, tx0);
        const float dy = fminf(py1, ty1) - fmaxf(py0, ty0);
        const float iw = fmaxf(dx, 0.f), ih = fmaxf(dy, 0.f);
        const float inter = iw * ih;
        const float ew = (pw + tw) - dx;                 // min-sum identity
        const float eh = (ph + th) - dy;
        const float ae = ew * eh;
        const float uni = __builtin_fmaf(-iw, ih, pa + ta);
        const float l1 = fabsf(pcx - tcx) + fabsf(pcy - tcy)
                       + fabsf(pw - tw)  + fabsf(ph - th);
        const float num = __builtin_fmaf(inter, ae, -(uni * (ae - uni)));
        const float g   = __fdividef(num, uni * ae);
        const float res = (ccv[p] + l1) - g;

        __builtin_nontemporal_store(res, obase + (size_t)p * 1600);
    }
}

extern "C" void kernel_launch(void* const* d_in, const int* in_sizes, int n_in,
                              void* d_out, int out_size, void* d_ws, size_t ws_size,
                              hipStream_t stream) {
    const float* pred_logits = (const float*)d_in[0];   // [16,1024,91]
    const float* pred_boxes  = (const float*)d_in[1];   // [16,1024,4]
    const float* pred_embed  = (const float*)d_in[2];   // [16,1024,512]
    const float* text_emb    = (const float*)d_in[3];   // [91,512]
    const int*   tgt_ids     = (const int*)d_in[4];     // [1600]
    const float* tgt_bbox    = (const float*)d_in[5];   // [1600,4]
    float* out = (float*)d_out;                         // [16384,1600]

    unsigned short* te_bf = (unsigned short*)d_ws;                    // 96*512*2 = 96 KB
    float* ccombo = (float*)((char*)d_ws + 102400);                   // 16384*96*4 = 6.29 MB

    k_prep<<<96, 256, 0, stream>>>(text_emb, te_bf);
    k_class_embed<<<1024, 256, 0, stream>>>(pred_logits, pred_embed, te_bf, ccombo);
    k_cost<<<512 * 25, 256, 0, stream>>>(pred_boxes, tgt_bbox, tgt_ids, ccombo, out);
}

// Round 8
// 68.531 us; speedup vs baseline: 1.1345x; 1.1345x over previous
//
#include <hip/hip_runtime.h>
#include <hip/hip_bf16.h>

using bf16x8 = __attribute__((ext_vector_type(8))) short;
using f32x4  = __attribute__((ext_vector_type(4))) float;

__device__ __forceinline__ unsigned short f2bf(float x) {
    unsigned int u = __float_as_uint(x);
    return (unsigned short)((u + 0x7FFFu + ((u >> 16) & 1u)) >> 16);
}

// -------------------------------------------------------------------------
// K0: pack text_embeddings [91][512] f32 -> [96][512] bf16 (rows 91..95 = 0)
// -------------------------------------------------------------------------
__global__ __launch_bounds__(256)
void k_prep(const float* __restrict__ te, unsigned short* __restrict__ te_bf) {
    const int r = blockIdx.x;            // 0..95
    for (int i = threadIdx.x; i < 512; i += 256) {
        const float v = (r < 91) ? te[(size_t)r * 512 + i] : 0.f;
        te_bf[(size_t)r * 512 + i] = f2bf(v);
    }
}

// -------------------------------------------------------------------------
// K1: ccombo[n][c] = focal(logits[n][c]) + 0.5*(1 - <v_norm[n], te[c]>)
// (R5 version, known-good) grid 1024, block 256 = 16 rows, 4-wave K-split.
// -------------------------------------------------------------------------
__global__ __launch_bounds__(256)
void k_class_embed(const float* __restrict__ logits,       // [16384][91]
                   const float* __restrict__ embed,        // [16384][512]
                   const unsigned short* __restrict__ te_bf, // [96][512] bf16
                   float* __restrict__ ccombo)             // [16384][96]
{
    __shared__ float accs[4][16 * 96];     // 24576 B
    __shared__ float sq_s[4][16];

    const int tid  = threadIdx.x;
    const int lane = tid & 63;
    const int wv   = tid >> 6;             // K-chunk 0..3
    const int r16  = lane & 15;
    const int q    = lane >> 4;
    const int n0   = blockIdx.x * 16;

    f32x4 acc[6];
#pragma unroll
    for (int j = 0; j < 6; ++j) acc[j] = (f32x4){0.f, 0.f, 0.f, 0.f};
    float sumsq = 0.f;

    const float* arow = embed + (size_t)(n0 + r16) * 512 + wv * 128 + q * 8;
#pragma unroll
    for (int ks = 0; ks < 4; ++ks) {
        const float4 a0 = *(const float4*)(arow + ks * 32);
        const float4 a1 = *(const float4*)(arow + ks * 32 + 4);
        const float fv[8] = {a0.x, a0.y, a0.z, a0.w, a1.x, a1.y, a1.z, a1.w};
        bf16x8 af;
#pragma unroll
        for (int j = 0; j < 8; ++j) {
            sumsq += fv[j] * fv[j];
            af[j] = (short)f2bf(fv[j]);
        }
#pragma unroll
        for (int ct = 0; ct < 6; ++ct) {
            const bf16x8 bfr = *(const bf16x8*)(te_bf + (size_t)(ct * 16 + r16) * 512
                                                + wv * 128 + ks * 32 + q * 8);
            acc[ct] = __builtin_amdgcn_mfma_f32_16x16x32_bf16(af, bfr, acc[ct], 0, 0, 0);
        }
    }
    sumsq += __shfl_xor(sumsq, 16);
    sumsq += __shfl_xor(sumsq, 32);
    if (lane < 16) sq_s[wv][r16] = sumsq;

#pragma unroll
    for (int ct = 0; ct < 6; ++ct)
#pragma unroll
        for (int j = 0; j < 4; ++j)
            accs[wv][(q * 4 + j) * 96 + ct * 16 + r16] = acc[ct][j];
    __syncthreads();

#pragma unroll
    for (int i = 0; i < 6; ++i) {
        const int e = tid + i * 256;                 // < 1536
        const int row = e / 96, col = e - row * 96;
        float v = 0.f;
        if (col < 91) {
            const float dot = accs[0][e] + accs[1][e] + accs[2][e] + accs[3][e];
            const float rn  = rsqrtf(sq_s[0][row] + sq_s[1][row] + sq_s[2][row] + sq_s[3][row]);
            const float x = logits[(size_t)(n0 + row) * 91 + col];
            const float p = 1.f / (1.f + __expf(-x));
            const float pos = 0.25f * (1.f - p) * (1.f - p) * (-__logf(p + 1e-8f));
            const float neg = 0.75f * p * p * (-__logf(1.f - p + 1e-8f));
            v = (pos - neg) + 0.5f - 0.5f * dot * rn;
        }
        ccombo[(size_t)n0 * 96 + e] = v;
    }
}

// -------------------------------------------------------------------------
// K2v5: out[n][m] = ccombo[n][id[m]] + L1 - GIoU
// grid 1024 = one block per 16 COMPLETE rows (contiguous 102.4 KB span).
// block 320 thr; thread owns 5 m-boxes (m = tid + j*320) in registers,
// loaded directly from global (L2-resident). LDS = cc_s 6 KB only.
// p-box per n via block-uniform s_load. NT scalar stores, 256 B/wave-instr.
// -------------------------------------------------------------------------
__global__ __launch_bounds__(320, 4)
void k_cost(const float* __restrict__ pboxes,   // [16384][4] cxcywh
            const float* __restrict__ tboxes,   // [1600][4]  cxcywh
            const int*   __restrict__ tids,     // [1600]
            const float* __restrict__ ccombo,   // [16384][96]
            float* __restrict__ out)            // [16384][1600]
{
    __shared__ float cc_s[16 * 96];   // 6144 B

    const int tid = threadIdx.x;
    const int n0  = blockIdx.x * 16;

    // stage cc rows [n0, n0+16): 1536 floats = 384 float4
    {
        const f32x4* src = (const f32x4*)(ccombo + (size_t)n0 * 96);
        f32x4* dst = (f32x4*)cc_s;
        for (int i = tid; i < 384; i += 320) dst[i] = src[i];
    }

    // per-thread 5 m-boxes straight from global into registers
    float tcx[5], tcy[5], tw[5], th[5];
    float tx0[5], ty0[5], tx1[5], ty1[5], ta[5];
    int ids[5];
#pragma unroll
    for (int j = 0; j < 5; ++j) {
        const int m = tid + j * 320;               // < 1600 always
        const float4 b = *(const float4*)(tboxes + (size_t)m * 4);
        tcx[j] = b.x; tcy[j] = b.y; tw[j] = b.z; th[j] = b.w;
        tx0[j] = __builtin_fmaf(-0.5f, b.z, b.x);
        ty0[j] = __builtin_fmaf(-0.5f, b.w, b.y);
        tx1[j] = __builtin_fmaf( 0.5f, b.z, b.x);
        ty1[j] = __builtin_fmaf( 0.5f, b.w, b.y);
        ta[j]  = b.z * b.w;
        ids[j] = tids[m];
    }
    __syncthreads();

#pragma unroll 4
    for (int n = 0; n < 16; ++n) {
        // block-uniform address -> s_load
        const float4 PB = *(const float4*)(pboxes + (size_t)(n0 + n) * 4);
        const float pcx = PB.x, pcy = PB.y, pw = PB.z, ph = PB.w;
        const float px0 = __builtin_fmaf(-0.5f, pw, pcx);
        const float py0 = __builtin_fmaf(-0.5f, ph, pcy);
        const float px1 = __builtin_fmaf( 0.5f, pw, pcx);
        const float py1 = __builtin_fmaf( 0.5f, ph, pcy);
        const float pa  = pw * ph;
        const float* ccrow = &cc_s[n * 96];
        float* orow = out + (size_t)(n0 + n) * 1600 + tid;

#pragma unroll
        for (int j = 0; j < 5; ++j) {
            const float dx = fminf(px1, tx1[j]) - fmaxf(px0, tx0[j]);
            const float dy = fminf(py1, ty1[j]) - fmaxf(py0, ty0[j]);
            const float iw = fmaxf(dx, 0.f), ih = fmaxf(dy, 0.f);
            const float inter = iw * ih;
            const float ew = (pw + tw[j]) - dx;        // min-sum identity
            const float eh = (ph + th[j]) - dy;
            const float ae = ew * eh;
            const float uni = __builtin_fmaf(-iw, ih, pa + ta[j]);
            const float l1 = fabsf(pcx - tcx[j]) + fabsf(pcy - tcy[j])
                           + fabsf(pw - tw[j])  + fabsf(ph - th[j]);
            const float num = __builtin_fmaf(inter, ae, -(uni * (ae - uni)));
            const float g   = __fdividef(num, uni * ae);
            const float res = (ccrow[ids[j]] + l1) - g;
            __builtin_nontemporal_store(res, orow + j * 320);
        }
    }
}

extern "C" void kernel_launch(void* const* d_in, const int* in_sizes, int n_in,
                              void* d_out, int out_size, void* d_ws, size_t ws_size,
                              hipStream_t stream) {
    const float* pred_logits = (const float*)d_in[0];   // [16,1024,91]
    const float* pred_boxes  = (const float*)d_in[1];   // [16,1024,4]
    const float* pred_embed  = (const float*)d_in[2];   // [16,1024,512]
    const float* text_emb    = (const float*)d_in[3];   // [91,512]
    const int*   tgt_ids     = (const int*)d_in[4];     // [1600]
    const float* tgt_bbox    = (const float*)d_in[5];   // [1600,4]
    float* out = (float*)d_out;                         // [16384,1600]

    unsigned short* te_bf = (unsigned short*)d_ws;                    // 96*512*2 = 96 KB
    float* ccombo = (float*)((char*)d_ws + 102400);                   // 16384*96*4 = 6.29 MB

    k_prep<<<96, 256, 0, stream>>>(text_emb, te_bf);
    k_class_embed<<<1024, 256, 0, stream>>>(pred_logits, pred_embed, te_bf, ccombo);
    k_cost<<<1024, 320, 0, stream>>>(pred_boxes, tgt_bbox, tgt_ids, ccombo, out);
}